// Round 1
// baseline (132.497 us; speedup 1.0000x reference)
//
#include <hip/hip_runtime.h>

#define F_ALPHA 0.25f
#define F_EPS   1e-8f

constexpr int B = 8, N = 16384, C = 80, M = 100;
constexpr int NT = 128;          // n per block
constexpr int THREADS = 256;     // 4 waves
constexpr int MPW = 25;          // m per wave (4 waves x 25 = 100)
constexpr int LDC = 81;          // padded LDS stride (odd -> conflict-free)

// ws layout (bytes):
//   ct_f   : B*M*C floats  = 256000   @ 0
//   b2area : B*M   floats  =   3200   @ 256000
//   clsid  : B*M   ints    =   3200   @ 259200
//   packed : B*M   u64     =   6400   @ 262400  (8-aligned)
constexpr size_t WS_CT   = 0;
constexpr size_t WS_A2   = 256000;
constexpr size_t WS_CID  = 259200;
constexpr size_t WS_PACK = 262400;

__device__ __forceinline__ unsigned ford(float f) {
    unsigned u = __float_as_uint(f);
    return (u & 0x80000000u) ? ~u : (u | 0x80000000u);
}

__device__ __forceinline__ float pair_total(float cls,
    float py0, float px0, float py1, float px1,
    float ty0, float tx0, float ty1, float tx1,
    float a1, float a2)
{
    float ih = fminf(py1, ty1) - fmaxf(py0, ty0);
    float iw = fminf(px1, tx1) - fmaxf(px0, tx0);
    float inter = fmaxf(ih, 0.f) * fmaxf(iw, 0.f);
    float uni = a1 + a2 - inter;
    float iou = (uni > 0.f) ? (inter / uni) : 0.f;
    float eh = fmaxf(py1, ty1) - fminf(py0, ty0);
    float ew = fmaxf(px1, tx1) - fminf(px0, tx0);
    float enc = fmaxf(eh, 0.f) * fmaxf(ew, 0.f);
    float g = iou - ((enc > 0.f) ? ((enc - uni) / enc) : 0.f);
    float gl = 1.f - g;
    float rg = fabsf(ty0 - py0) + fabsf(tx0 - px0) +
               fabsf(ty1 - py1) + fabsf(tx1 - px1);
    return 2.f * cls + 5.f * rg + 2.f * gl;
}

__global__ void prep_kernel(const int* __restrict__ cls_true,
                            const float* __restrict__ loc_true,
                            float* __restrict__ ct_f,
                            float* __restrict__ b2area,
                            int* __restrict__ clsid,
                            unsigned long long* __restrict__ packed)
{
    int idx = blockIdx.x * blockDim.x + threadIdx.x;
    if (idx >= B * M) return;
    int cid = 0;
    bool found = false;
    for (int c = 0; c < C; ++c) {
        int v = cls_true[idx * C + c];
        float f = (v == 1) ? 1.0f : 0.0f;
        ct_f[idx * C + c] = f;
        if (!found && v == 1) { cid = c; found = true; }
    }
    clsid[idx] = cid;
    float y0 = loc_true[idx * 4 + 0], x0 = loc_true[idx * 4 + 1];
    float y1 = loc_true[idx * 4 + 2], x1 = loc_true[idx * 4 + 3];
    b2area[idx] = fmaxf(y1 - y0, 0.f) * fmaxf(x1 - x0, 0.f);
    packed[idx] = 0xFFFFFFFFFFFFFFFFull;
}

__global__ __launch_bounds__(THREADS, 2)
void match_kernel(const float* __restrict__ cls_pred,
                  const float* __restrict__ loc_pred,
                  const float* __restrict__ ct_f,
                  const float* __restrict__ loc_true,
                  const float* __restrict__ b2area,
                  unsigned long long* __restrict__ packed)
{
    __shared__ float s_diff[NT][LDC];
    __shared__ float s_ct[M][LDC];
    __shared__ float s_lt[M][4];
    __shared__ float s_a2[M];

    const int b  = blockIdx.y;
    const int n0 = blockIdx.x * NT;
    const int t  = threadIdx.x;
    const int w  = t >> 6;       // wave id 0..3
    const int l  = t & 63;       // lane

    // ---- stage diff = pos_cost - neg_cost into LDS ----
    const float4* cp4 = (const float4*)(cls_pred + ((size_t)b * N + n0) * C);
    for (int i = t; i < NT * C / 4; i += THREADS) {
        float4 v = cp4[i];
        int e = i * 4;
        int nl = e / C, c = e % C;
        float pv[4] = { v.x, v.y, v.z, v.w };
        #pragma unroll
        for (int j = 0; j < 4; ++j) {
            float p = pv[j];
            float q = 1.0f - p;
            float pos = F_ALPHA * q * q * (-logf(p + F_EPS));
            float neg = (1.0f - F_ALPHA) * p * p * (-logf(q + F_EPS));
            s_diff[nl][c + j] = pos - neg;
        }
    }
    // ---- stage ct floats ----
    for (int i = t; i < M * C; i += THREADS) {
        s_ct[i / C][i % C] = ct_f[(size_t)b * M * C + i];
    }
    // ---- stage loc_true + areas ----
    for (int i = t; i < M * 4; i += THREADS) {
        s_lt[i / 4][i % 4] = loc_true[(size_t)b * M * 4 + i];
    }
    for (int i = t; i < M; i += THREADS) {
        s_a2[i] = b2area[(size_t)b * M + i];
    }
    __syncthreads();

    // ---- per-lane n pair ----
    const int nA = n0 + l;
    const int nB = n0 + l + 64;
    float4 lpA = ((const float4*)loc_pred)[(size_t)b * N + nA];
    float4 lpB = ((const float4*)loc_pred)[(size_t)b * N + nB];
    float a1A = fmaxf(lpA.z - lpA.x, 0.f) * fmaxf(lpA.w - lpA.y, 0.f);
    float a1B = fmaxf(lpB.z - lpB.x, 0.f) * fmaxf(lpB.w - lpB.y, 0.f);

    float acc[MPW][2];
    #pragma unroll
    for (int j = 0; j < MPW; ++j) { acc[j][0] = 0.f; acc[j][1] = 0.f; }

    for (int c = 0; c < C; ++c) {
        float dA = s_diff[l][c];
        float dB = s_diff[l + 64][c];
        #pragma unroll
        for (int j = 0; j < MPW; ++j) {
            float cv = s_ct[w + 4 * j][c];
            acc[j][0] = fmaf(dA, cv, acc[j][0]);
            acc[j][1] = fmaf(dB, cv, acc[j][1]);
        }
    }

    // ---- epilogue: totals, pack, wave-reduce argmin, atomic ----
    #pragma unroll
    for (int j = 0; j < MPW; ++j) {
        const int m = w + 4 * j;
        float ty0 = s_lt[m][0], tx0 = s_lt[m][1];
        float ty1 = s_lt[m][2], tx1 = s_lt[m][3];
        float a2  = s_a2[m];
        float totA = pair_total(acc[j][0], lpA.x, lpA.y, lpA.z, lpA.w,
                                ty0, tx0, ty1, tx1, a1A, a2);
        float totB = pair_total(acc[j][1], lpB.x, lpB.y, lpB.z, lpB.w,
                                ty0, tx0, ty1, tx1, a1B, a2);
        unsigned long long pA = (((unsigned long long)ford(totA)) << 32) | (unsigned)nA;
        unsigned long long pB = (((unsigned long long)ford(totB)) << 32) | (unsigned)nB;
        unsigned long long pmin = (pA < pB) ? pA : pB;
        #pragma unroll
        for (int off = 32; off >= 1; off >>= 1) {
            unsigned long long other = __shfl_xor(pmin, off, 64);
            if (other < pmin) pmin = other;
        }
        if (l == 0) {
            atomicMin(&packed[(size_t)b * M + m], pmin);
        }
    }
}

__global__ void out_kernel(const unsigned long long* __restrict__ packed,
                           const int* __restrict__ clsid,
                           int* __restrict__ out)
{
    int idx = blockIdx.x * blockDim.x + threadIdx.x;
    if (idx >= B * M) return;
    int b = idx / M;
    out[idx * 3 + 0] = b;
    out[idx * 3 + 1] = (int)(unsigned)(packed[idx] & 0xFFFFFFFFull);
    out[idx * 3 + 2] = clsid[idx];
}

extern "C" void kernel_launch(void* const* d_in, const int* in_sizes, int n_in,
                              void* d_out, int out_size, void* d_ws, size_t ws_size,
                              hipStream_t stream)
{
    const float* cls_pred = (const float*)d_in[0];
    const float* loc_pred = (const float*)d_in[1];
    const int*   cls_true = (const int*)d_in[2];
    const float* loc_true = (const float*)d_in[3];
    // d_in[4] = reg_mask (unused by the reference output)

    char* ws = (char*)d_ws;
    float* ct_f   = (float*)(ws + WS_CT);
    float* b2area = (float*)(ws + WS_A2);
    int*   clsid  = (int*)(ws + WS_CID);
    unsigned long long* packed = (unsigned long long*)(ws + WS_PACK);

    int* out = (int*)d_out;

    prep_kernel<<<(B * M + 255) / 256, 256, 0, stream>>>(
        cls_true, loc_true, ct_f, b2area, clsid, packed);

    dim3 grid(N / NT, B);
    match_kernel<<<grid, THREADS, 0, stream>>>(
        cls_pred, loc_pred, ct_f, loc_true, b2area, packed);

    out_kernel<<<(B * M + 255) / 256, 256, 0, stream>>>(packed, clsid, out);
}